// Round 11
// baseline (113.906 us; speedup 1.0000x reference)
//
#include <hip/hip_runtime.h>
#include <math.h>

// EEG_Deformer — bit-faithful to jax-CPU XLA f32 (PASS R8-R10, absmax 0.03125).
// Bit-exactness contract (do not alter):
//   tanh: XLA EmitFastTanh with_fma (clamp ±7.99881172180175781)
//   conv: Eigen true-FMA chain, ascending taps, acc from 0; bias separate add
//   pos = ((off + t) + n) + 7, unfused adds; only floor(pos) reaches output
//   rcp fast-div + 1e-3 integer-proximity guard (proven floor-safe R10)
// Perf (R11): pack the two unrolled t-streams (t, t+BLK) into float2 so the
// conv/poly/pos arithmetic emits VOP3P v_pk_{fma,mul,add}_f32 — one wave-instr
// per TWO f32 ops. R10 was issue-limited at ~355 VALU instr/output.

typedef float f32x2 __attribute__((ext_vector_type(2)));

constexpr int KK   = 5;
constexpr int TT   = 4000;
constexpr int HEAD = 7;                 // K//2 + L
constexpr int TAIL = 7;                 // (K-1)//2 + L
constexpr int TEXT = TT + HEAD + TAIL;  // 4014
constexpr int BLK  = 256;

__device__ __forceinline__ f32x2 splat(float v) { return (f32x2){v, v}; }

// scalar path (tail + guard fallback) — bit-identical to R10's proc1
__device__ __forceinline__ float proc1(const float* __restrict__ xe,
                                       const float (&w)[KK][KK],
                                       const float (&bv)[KK],
                                       int t)
{
#pragma clang fp contract(off)
    const float tf = (float)t;
    float xv[KK];
    if (t >= 2 && t < TT - 2) {
#pragma unroll
        for (int j = 0; j < KK; ++j) xv[j] = xe[HEAD + t + j - 2];
    } else {
#pragma unroll
        for (int j = 0; j < KK; ++j) {
            const int u = t + j - 2;
            xv[j] = (u >= 0 && u < TT) ? xe[HEAD + u] : 0.0f;
        }
    }
    float acc = 0.0f;
#pragma unroll
    for (int k = 0; k < KK; ++k) {
        float s = 0.0f;
#pragma unroll
        for (int j = 0; j < KK; ++j) s = __builtin_fmaf(xv[j], w[k][j], s);
        s = s + bv[k];
        const float clampv = 7.99881172180175781f;
        const float xx = fminf(fmaxf(s, -clampv), clampv);
        const float x2 = xx * xx;
        float p = -2.76076847742355e-16f;
        p = __builtin_fmaf(x2, p, 2.00018790482477e-13f);
        p = __builtin_fmaf(x2, p, -8.60467152213735e-11f);
        p = __builtin_fmaf(x2, p, 5.12229709037114e-08f);
        p = __builtin_fmaf(x2, p, 1.48572235717979e-05f);
        p = __builtin_fmaf(x2, p, 6.37261928875436e-04f);
        p = __builtin_fmaf(x2, p, 4.89352455891786e-03f);
        const float num = xx * p;
        float q = 1.19825839466702e-06f;
        q = __builtin_fmaf(x2, q, 1.18534705686654e-04f);
        q = __builtin_fmaf(x2, q, 2.26843463243900e-03f);
        q = __builtin_fmaf(x2, q, 4.89352518554385e-03f);
        float th = num * __builtin_amdgcn_rcpf(q);
        if (fabsf(s) < 0.0004f) th = s;
        float pos = (th * 5.0f) + tf;
        pos = pos + (float)(k - 2);
        pos = pos + 7.0f;
        const float dd = pos - rintf(pos);
        if (fabsf(dd) < 1e-3f) {
            float thx = num / q;
            if (fabsf(s) < 0.0004f) thx = s;
            float posx = (thx * 5.0f) + tf;
            posx = posx + (float)(k - 2);
            posx = posx + 7.0f;
            pos = posx;
        }
        acc = acc + xe[(int)pos];
    }
    return acc;
}

// packed path: elements .x -> t, .y -> t+BLK
__device__ __forceinline__ void proc2(const float* __restrict__ xe,
                                      const float (&w)[KK][KK],
                                      const float (&bv)[KK],
                                      int t, float& o0, float& o1)
{
#pragma clang fp contract(off)
    const int t1 = t + BLK;
    const f32x2 tf = {(float)t, (float)t1};

    f32x2 xv[KK];
    if (t >= 2 && t1 < TT - 2) {
#pragma unroll
        for (int j = 0; j < KK; ++j)
            xv[j] = (f32x2){xe[HEAD + t + j - 2], xe[HEAD + t1 + j - 2]};
    } else {
#pragma unroll
        for (int j = 0; j < KK; ++j) {
            const int u0 = t + j - 2, u1 = t1 + j - 2;
            xv[j] = (f32x2){(u0 >= 0 && u0 < TT) ? xe[HEAD + u0] : 0.0f,
                            (u1 >= 0 && u1 < TT) ? xe[HEAD + u1] : 0.0f};
        }
    }

    float a0 = 0.0f, a1 = 0.0f;
#pragma unroll
    for (int k = 0; k < KK; ++k) {
        // conv: packed true-FMA chain (v_pk_fma_f32), ascending j, acc from 0
        f32x2 s = splat(0.0f);
#pragma unroll
        for (int j = 0; j < KK; ++j)
            s = __builtin_elementwise_fma(xv[j], splat(w[k][j]), s);
        s = s + splat(bv[k]);                       // unfused packed add

        const float clampv = 7.99881172180175781f;
        f32x2 xx = __builtin_elementwise_min(
                       __builtin_elementwise_max(s, splat(-clampv)), splat(clampv));
        f32x2 x2 = xx * xx;                         // packed mul
        f32x2 p = splat(-2.76076847742355e-16f);
        p = __builtin_elementwise_fma(x2, p, splat(2.00018790482477e-13f));
        p = __builtin_elementwise_fma(x2, p, splat(-8.60467152213735e-11f));
        p = __builtin_elementwise_fma(x2, p, splat(5.12229709037114e-08f));
        p = __builtin_elementwise_fma(x2, p, splat(1.48572235717979e-05f));
        p = __builtin_elementwise_fma(x2, p, splat(6.37261928875436e-04f));
        p = __builtin_elementwise_fma(x2, p, splat(4.89352455891786e-03f));
        f32x2 num = xx * p;                         // packed mul
        f32x2 q = splat(1.19825839466702e-06f);
        q = __builtin_elementwise_fma(x2, q, splat(1.18534705686654e-04f));
        q = __builtin_elementwise_fma(x2, q, splat(2.26843463243900e-03f));
        q = __builtin_elementwise_fma(x2, q, splat(4.89352518554385e-03f));

        f32x2 rcpv = {__builtin_amdgcn_rcpf(q.x), __builtin_amdgcn_rcpf(q.y)};
        f32x2 th = num * rcpv;                      // packed mul
        if (fabsf(s.x) < 0.0004f) th.x = s.x;       // passthrough, per element
        if (fabsf(s.y) < 0.0004f) th.y = s.y;
        f32x2 pos = (th * splat(5.0f)) + tf;        // packed mul, packed add
        pos = pos + splat((float)(k - 2));
        pos = pos + splat(7.0f);

        // guard: redo with exact IEEE div if within 1e-3 of an integer
        // (fast-vs-exact pos differ <= 1 ulp <= 2.44e-4 -> provably floor-safe)
        const float dd0 = pos.x - rintf(pos.x);
        if (fabsf(dd0) < 1e-3f) {
            float thx = num.x / q.x;
            if (fabsf(s.x) < 0.0004f) thx = s.x;
            float px = (thx * 5.0f) + tf.x;
            px = px + (float)(k - 2);
            px = px + 7.0f;
            pos.x = px;
        }
        const float dd1 = pos.y - rintf(pos.y);
        if (fabsf(dd1) < 1e-3f) {
            float thx = num.y / q.y;
            if (fabsf(s.y) < 0.0004f) thx = s.y;
            float px = (thx * 5.0f) + tf.y;
            px = px + (float)(k - 2);
            px = px + 7.0f;
            pos.y = px;
        }

        // pos in [t, t+14] ⊆ [0, 4013]; (int) == floor for >= 0
        a0 = a0 + xe[(int)pos.x];
        a1 = a1 + xe[(int)pos.y];
    }
    o0 = a0; o1 = a1;
}

__global__ __launch_bounds__(BLK) void eeg_deform_kernel(
    const float* __restrict__ x,
    const float* __restrict__ w_off,
    const float* __restrict__ b_off,
    float* __restrict__ out)
{
#pragma clang fp contract(off)
    __shared__ float xe[TEXT];   // x_ext for this row

    const int row = blockIdx.x;                    // b*C + c
    const float* __restrict__ xr = x + (size_t)row * TT;
    float* __restrict__ outr      = out + (size_t)row * TT;
    const int tid = threadIdx.x;

    // ---- stage row into LDS as x_ext (vectorized float4)
    const float4* __restrict__ xr4 = reinterpret_cast<const float4*>(xr);
    for (int i = tid; i < TT / 4; i += BLK) {
        float4 v = xr4[i];
        xe[HEAD + 4 * i + 0] = v.x;
        xe[HEAD + 4 * i + 1] = v.y;
        xe[HEAD + 4 * i + 2] = v.z;
        xe[HEAD + 4 * i + 3] = v.w;
    }
    if (tid < HEAD) {
        xe[tid] = xr[TT - TAIL + tid];             // wrap: last 7 of x
    } else if (tid >= BLK - TAIL) {
        int j = tid - (BLK - TAIL);
        xe[HEAD + TT + j] = xr[j];                 // wrap: first 7 of x
    }

    // ---- weights/bias (uniform -> SGPRs)
    float w[KK][KK];
    float bv[KK];
#pragma unroll
    for (int k = 0; k < KK; ++k) {
        bv[k] = b_off[k];
#pragma unroll
        for (int j = 0; j < KK; ++j) w[k][j] = w_off[k * KK + j];
    }

    __syncthreads();

    // ---- main loop: packed pairs (t, t+BLK), scalar tail
    int t = tid;
    for (; t + BLK < TT; t += 2 * BLK) {
        float a0, a1;
        proc2(xe, w, bv, t, a0, a1);
        outr[t]       = a0;
        outr[t + BLK] = a1;
    }
    for (; t < TT; t += BLK) {
        outr[t] = proc1(xe, w, bv, t);
    }
}

extern "C" void kernel_launch(void* const* d_in, const int* in_sizes, int n_in,
                              void* d_out, int out_size, void* d_ws, size_t ws_size,
                              hipStream_t stream) {
    const float* x     = (const float*)d_in[0];
    const float* w_off = (const float*)d_in[1];
    const float* b_off = (const float*)d_in[2];
    float* out         = (float*)d_out;

    const int rows = in_sizes[0] / TT;             // B*C = 2048
    eeg_deform_kernel<<<rows, BLK, 0, stream>>>(x, w_off, b_off, out);
}